// Round 3
// baseline (3456.530 us; speedup 1.0000x reference)
//
#include <hip/hip_runtime.h>
#include <stdint.h>

// GTCN2 Round 8:
//  - SpMM restructured for 2x in-flight gather bytes: lane owns 8 features
//    (16B ushort8), 32 lanes cover the row, the two wave halves process
//    DIFFERENT edges in the same VMEM instruction (1KiB/instr, 2 edges).
//    4-deep unroll = 8 edges / 4 KB in flight per wave (was 4 edges / 2 KB).
//    CSR entries for the next batch prefetched before the FMA chain.
//    Cross-half combine via __shfl_xor(...,32) once per row.
//  - CSR build (two-pass bucketed) and GEMMs unchanged from R7.

typedef unsigned short bf16_t;
typedef __attribute__((ext_vector_type(8))) short bf16x8;
typedef __attribute__((ext_vector_type(8))) unsigned short u16x8;
typedef __attribute__((ext_vector_type(4))) float f32x4;

__device__ __forceinline__ float bf2f(bf16_t u) {
    union { unsigned int i; float f; } v; v.i = ((unsigned int)u) << 16; return v.f;
}
__device__ __forceinline__ bf16_t f2bf(float f) {
    union { float f; unsigned int i; } v; v.f = f;
    unsigned int x = v.i;
    unsigned int r = (x + 0x7fffu + ((x >> 16) & 1u)) >> 16;  // RNE
    return (bf16_t)r;
}

__global__ void zero_i32(int* __restrict__ p, int n) {
    int i = blockIdx.x * blockDim.x + threadIdx.x;
    if (i < n) p[i] = 0;
}

// W: KxN fp32 -> Wt: NxK bf16 (so GEMM B-staging == A-staging pattern).
__global__ void transpose_w(const float* __restrict__ W, bf16_t* __restrict__ Wt,
                            int K, int N) {
    int i = blockIdx.x * blockDim.x + threadIdx.x;
    if (i < K * N) {
        int k = i / N, n = i % N;
        Wt[(size_t)n * K + k] = f2bf(W[i]);
    }
}

// Per-row counts. Predicate: r in range only (invalid-c edges become val=0
// entries downstream, keeping slot accounting consistent).
__global__ void count_edges(const int* __restrict__ er, int* __restrict__ cnt,
                            int E, int N) {
    int i = blockIdx.x * blockDim.x + threadIdx.x;
    if (i < E) {
        unsigned r = (unsigned)er[i];
        if (r < (unsigned)N) atomicAdd(&cnt[r], 1);
    }
}

__global__ __launch_bounds__(1024)
void scan_rows(int* cnt_cursor, int* __restrict__ row_ptr, int n) {
    __shared__ int sums[1024];
    int t = threadIdx.x;
    int chunk = (n + 1023) >> 10;
    int start = t * chunk;
    int end = min(start + chunk, n);
    int s = 0;
    for (int i = start; i < end; ++i) s += cnt_cursor[i];
    sums[t] = s;
    __syncthreads();
    for (int off = 1; off < 1024; off <<= 1) {
        int v = (t >= off) ? sums[t - off] : 0;
        __syncthreads();
        sums[t] += v;
        __syncthreads();
    }
    int run = (t == 0) ? 0 : sums[t - 1];
    for (int i = start; i < end; ++i) {
        int c = cnt_cursor[i];
        row_ptr[i] = run;
        run += c;
    }
    if (t == 1023) row_ptr[n] = sums[1023];
}

__global__ void init_bcur(const int* __restrict__ row_ptr, int* __restrict__ bcur,
                          int N, int NB) {
    int b = blockIdx.x * blockDim.x + threadIdx.x;
    if (b < NB) bcur[b] = row_ptr[min(b << 8, N)];
}

// Pass 1: bin edges into 256-row buckets. Packed entry: .x = r_local<<17 | c
// (c < 2^17), .y = float bits of val.
#define BIN_CHUNK 8192
#define NBMAX 392
__global__ __launch_bounds__(256)
void bin_edges(const int* __restrict__ er, const int* __restrict__ ec,
               const float* __restrict__ ev, int* __restrict__ bcur,
               int2* __restrict__ binned, int E, int N, int NB) {
    __shared__ int cnt[NBMAX];
    __shared__ int resv[NBMAX];
    int tid = threadIdx.x;
    int e0 = blockIdx.x * BIN_CHUNK;
    int n = min(BIN_CHUNK, E - e0);
    for (int b = tid; b < NB; b += 256) cnt[b] = 0;
    __syncthreads();
    for (int i = tid; i < n; i += 256) {
        unsigned r = (unsigned)er[e0 + i];
        if (r < (unsigned)N) atomicAdd(&cnt[r >> 8], 1);
    }
    __syncthreads();
    for (int b = tid; b < NB; b += 256) {
        int c = cnt[b];
        resv[b] = c ? atomicAdd(&bcur[b], c) : 0;
        cnt[b] = 0;  // reuse as local cursor
    }
    __syncthreads();
    for (int i = tid; i < n; i += 256) {
        unsigned r = (unsigned)er[e0 + i];
        if (r < (unsigned)N) {
            unsigned c = (unsigned)ec[e0 + i];
            float v = ev[e0 + i];
            if (c >= (unsigned)N) { c = 0; v = 0.f; }  // sanitize, keep slot
            int b = (int)(r >> 8);
            int p = resv[b] + atomicAdd(&cnt[b], 1);
            binned[p] = make_int2((int)(((r & 255u) << 17) | c), __float_as_int(v));
        }
    }
}

// Pass 2: sort one bucket into exact CSR row order, in place via LDS staging.
#define BCAP 9216
__global__ __launch_bounds__(256)
void bucket_sort(const int* __restrict__ row_ptr, int2* __restrict__ csr, int N) {
    __shared__ int2 ent[BCAP];
    __shared__ int cnt[256];
    __shared__ int base[256];
    __shared__ int lcur[256];
    int b = blockIdx.x;
    int tid = threadIdx.x;
    int r0 = b << 8;
    int e0 = row_ptr[r0];
    int e1 = row_ptr[min(r0 + 256, N)];
    int n = e1 - e0;
    cnt[tid] = 0;
    __syncthreads();
    for (int i = tid; i < n; i += 256) {
        int2 p = csr[e0 + i];
        if (i < BCAP) ent[i] = p;
        atomicAdd(&cnt[((unsigned)p.x >> 17) & 255u], 1);
    }
    __syncthreads();
    int v0 = cnt[tid];
    for (int off = 1; off < 256; off <<= 1) {
        int u = (tid >= off) ? cnt[tid - off] : 0;
        __syncthreads();
        cnt[tid] += u;
        __syncthreads();
    }
    base[tid] = cnt[tid] - v0;  // exclusive scan
    lcur[tid] = 0;
    __syncthreads();
    for (int i = tid; i < n; i += 256) {
        int2 p = (i < BCAP) ? ent[i] : csr[e0 + i];  // tail branch unreachable
        int rl = (int)(((unsigned)p.x >> 17) & 255u);
        int d = base[rl] + atomicAdd(&lcur[rl], 1);
        csr[e0 + d] = make_int2(p.x & 0x1FFFF, p.y);
    }
}

__device__ __forceinline__ void fma8(float* acc, float v, u16x8 hv) {
    #pragma unroll
    for (int k = 0; k < 8; ++k)
        acc[k] = fmaf(v, bf2f((bf16_t)hv[k]), acc[k]);
}

// s[row,:] = A2[row]*x0[row,:] + sum_e val[e]*h[col[e],:]
// One wave per row; lane owns 8 features (16B), 32 lanes cover the row,
// wave halves process different edges -> 1KiB / 2 edges per VMEM instr.
// 8 edges (4 instrs, 4KB) in flight per wave; csr prefetched one batch ahead.
__global__ __launch_bounds__(256)
void spmm_kernel(const int* __restrict__ row_ptr, const int2* __restrict__ csr,
                 const bf16_t* __restrict__ h, const bf16_t* __restrict__ x0,
                 const float* __restrict__ A2, bf16_t* __restrict__ s, int N) {
    int w = threadIdx.x >> 6;
    int lane = threadIdx.x & 63;
    int row = (blockIdx.x << 2) + w;
    if (row >= N) return;
    int half = lane >> 5;
    int l32 = lane & 31;
    int fo = l32 << 3;                  // 8 features per lane (NH=256)
    int base = (row << 8) + fo;

    float acc[8];
    if (half == 0) {
        float a2 = A2[row];
        u16x8 xv = *(const u16x8*)&x0[base];
        #pragma unroll
        for (int k = 0; k < 8; ++k) acc[k] = a2 * bf2f((bf16_t)xv[k]);
    } else {
        #pragma unroll
        for (int k = 0; k < 8; ++k) acc[k] = 0.f;
    }

    int e = row_ptr[row], e1 = row_ptr[row + 1];
    int nb = (e1 - e) >> 3;             // full 8-edge batches
    int2 q0, q1, q2, q3;
    if (nb > 0) {
        int eb = e + half;
        q0 = csr[eb]; q1 = csr[eb + 2]; q2 = csr[eb + 4]; q3 = csr[eb + 6];
    }
    for (int b = 0; b < nb; ++b) {
        int2 p0 = q0, p1 = q1, p2 = q2, p3 = q3;
        if (b + 1 < nb) {
            int eb = e + 8 + half;      // prefetch next batch's csr entries
            q0 = csr[eb]; q1 = csr[eb + 2]; q2 = csr[eb + 4]; q3 = csr[eb + 6];
        }
        u16x8 h0 = *(const u16x8*)&h[(p0.x << 8) + fo];
        u16x8 h1 = *(const u16x8*)&h[(p1.x << 8) + fo];
        u16x8 h2 = *(const u16x8*)&h[(p2.x << 8) + fo];
        u16x8 h3 = *(const u16x8*)&h[(p3.x << 8) + fo];
        fma8(acc, __int_as_float(p0.y), h0);
        fma8(acc, __int_as_float(p1.y), h1);
        fma8(acc, __int_as_float(p2.y), h2);
        fma8(acc, __int_as_float(p3.y), h3);
        e += 8;
    }
    for (; e + 2 <= e1; e += 2) {       // pair tail (both halves active)
        int2 p = csr[e + half];
        u16x8 hv = *(const u16x8*)&h[(p.x << 8) + fo];
        fma8(acc, __int_as_float(p.y), hv);
    }
    if (e < e1 && half == 0) {          // odd last edge on half 0
        int2 p = csr[e];
        u16x8 hv = *(const u16x8*)&h[(p.x << 8) + fo];
        fma8(acc, __int_as_float(p.y), hv);
    }

    #pragma unroll
    for (int k = 0; k < 8; ++k) acc[k] += __shfl_xor(acc[k], 32, 64);
    if (half == 0) {
        u16x8 o;
        #pragma unroll
        for (int k = 0; k < 8; ++k) o[k] = f2bf(acc[k]);
        *(u16x8*)&s[base] = o;          // 32 lanes x 16B = 512B per row
    }
}

// MFMA GEMM: C[M,Nfull] = epi(A[M,K] @ Bt[Nfull,K]^T).
// Tile: (WM*64) x (WN*64), 4 waves, each wave 64x64 via 4x4 of 16x16x32 MFMA.
// BK=32. A bf16 (global_load_lds) or fp32 (convert-in-LDS). Bt bf16 NxK.
// SKIP: C += A[row,col] (requires Nfull<=K, hop skip). RELU on epilogue.
template <int WM, int WN, bool AF32, bool SKIP, bool RELU, typename CT>
__global__ __launch_bounds__(256)
void mfma_gemm(const void* __restrict__ Av, const bf16_t* __restrict__ Bt,
               const float* __restrict__ bias, CT* __restrict__ C,
               int M, int K, int Nfull) {
    constexpr int TM = WM * 64;
    constexpr int TN = WN * 64;
    __shared__ bf16_t As[TM * 32];
    __shared__ bf16_t Bs[TN * 32];
    const int tid = threadIdx.x;
    const int w = tid >> 6, lane = tid & 63;
    const int q = lane >> 4, l16 = lane & 15;
    const int bm = blockIdx.x * TM;
    const int bn = blockIdx.y * TN;
    const int wm = (w % WM) * 64;
    const int wn = (w / WM) * 64;

    f32x4 acc[4][4] = {};

    for (int k0 = 0; k0 < K; k0 += 32) {
        // ---- stage A tile [TM][32] ----
        if constexpr (AF32) {
            // TM must be 128 here: thread t covers row t/2, 16 elements.
            const float* A = (const float*)Av;
            int row = tid >> 1;
            int gr = min(bm + row, M - 1);
            const float* src = A + (size_t)gr * K + k0 + (tid & 1) * 16;
            bf16_t* dst = As + row * 32 + (tid & 1) * 16;
            #pragma unroll
            for (int g = 0; g < 4; ++g) {
                float4 v = *(const float4*)(src + 4 * g);
                ushort4 u;
                u.x = f2bf(v.x); u.y = f2bf(v.y); u.z = f2bf(v.z); u.w = f2bf(v.w);
                *(ushort4*)(dst + 4 * g) = u;
            }
        } else {
            const bf16_t* A = (const bf16_t*)Av;
            #pragma unroll
            for (int r = 0; r < TM / 64; ++r) {
                int rowbase = r * 64 + w * 16;           // wave-uniform
                int row = rowbase + (lane >> 2);
                int gr = min(bm + row, M - 1);           // clamp tail rows
                const bf16_t* gp = A + (size_t)gr * K + k0 + (lane & 3) * 8;
                bf16_t* lp = As + rowbase * 32 + lane * 8; // contiguous lane order
                __builtin_amdgcn_global_load_lds(
                    (const __attribute__((address_space(1))) unsigned int*)gp,
                    (__attribute__((address_space(3))) unsigned int*)lp, 16, 0, 0);
            }
        }
        // ---- stage B tile [TN][32] from Bt (NxK row-major) ----
        #pragma unroll
        for (int r = 0; r < TN / 64; ++r) {
            int rowbase = r * 64 + w * 16;
            int row = rowbase + (lane >> 2);
            const bf16_t* gp = Bt + (size_t)(bn + row) * K + k0 + (lane & 3) * 8;
            bf16_t* lp = Bs + rowbase * 32 + lane * 8;
            __builtin_amdgcn_global_load_lds(
                (const __attribute__((address_space(1))) unsigned int*)gp,
                (__attribute__((address_space(3))) unsigned int*)lp, 16, 0, 0);
        }
        __syncthreads();  // drains vmcnt (global_load_lds) + lgkm, then barrier

        bf16x8 afr[4], bfr[4];
        #pragma unroll
        for (int ms = 0; ms < 4; ++ms)
            afr[ms] = *(const bf16x8*)&As[(wm + ms * 16 + l16) * 32 + q * 8];
        #pragma unroll
        for (int ns = 0; ns < 4; ++ns)
            bfr[ns] = *(const bf16x8*)&Bs[(wn + ns * 16 + l16) * 32 + q * 8];
        #pragma unroll
        for (int ms = 0; ms < 4; ++ms)
            #pragma unroll
            for (int ns = 0; ns < 4; ++ns)
                acc[ms][ns] = __builtin_amdgcn_mfma_f32_16x16x32_bf16(
                    afr[ms], bfr[ns], acc[ms][ns], 0, 0, 0);
        __syncthreads();  // LDS consumed; safe to overwrite next iter
    }

    // ---- epilogue: C/D layout col=lane&15, row=quad*4+reg ----
    const bf16_t* Askip = (const bf16_t*)Av;  // used only when SKIP (bf16 A)
    #pragma unroll
    for (int ms = 0; ms < 4; ++ms) {
        #pragma unroll
        for (int r = 0; r < 4; ++r) {
            int row = bm + wm + ms * 16 + q * 4 + r;
            if (row < M) {
                #pragma unroll
                for (int ns = 0; ns < 4; ++ns) {
                    int col = bn + wn + ns * 16 + l16;
                    float v = acc[ms][ns][r] + bias[col];
                    if constexpr (SKIP) v += bf2f(Askip[(size_t)row * K + col]);
                    if constexpr (RELU) v = fmaxf(v, 0.f);
                    if constexpr (sizeof(CT) == 2) C[(size_t)row * Nfull + col] = (CT)f2bf(v);
                    else                           C[(size_t)row * Nfull + col] = (CT)v;
                }
            }
        }
    }
}

extern "C" void kernel_launch(void* const* d_in, const int* in_sizes, int n_in,
                              void* d_out, int out_size, void* d_ws, size_t ws_size,
                              hipStream_t stream) {
    const float* x   = (const float*)d_in[0];
    const int* erow  = (const int*)d_in[1];
    const int* ecol  = (const int*)d_in[2];
    const float* ev  = (const float*)d_in[3];
    const float* A2  = (const float*)d_in[4];
    const float* W1  = (const float*)d_in[5];
    const float* b1  = (const float*)d_in[6];
    const float* W3  = (const float*)d_in[7];
    const float* b3  = (const float*)d_in[8];
    const float* W2  = (const float*)d_in[9];
    const float* b2  = (const float*)d_in[10];
    float* out = (float*)d_out;

    const int N   = in_sizes[4];        // 100000 nodes
    const int E   = in_sizes[1];        // 3200000 edges
    const int NIN = in_sizes[0] / N;    // 512
    const int NH  = in_sizes[6];        // 256
    const int NO  = in_sizes[10];       // 64
    if (NH != 256 || NIN != 512 || NO != 64) return;  // layout hard-coded
    const int NB = (N + 255) >> 8;      // 391 buckets
    if (NB > NBMAX) return;

    char* ws = (char*)d_ws;
    size_t off = 0;
    auto alloc = [&](size_t bytes) -> void* {
        void* p = ws + off;
        off += (bytes + 255) & ~(size_t)255;
        return p;
    };
    bf16_t* x0     = (bf16_t*)alloc((size_t)N * NH * 2);
    bf16_t* hA     = (bf16_t*)alloc((size_t)N * NH * 2);
    bf16_t* hB     = (bf16_t*)alloc((size_t)N * NH * 2);
    int*   row_ptr = (int*)alloc((size_t)(N + 1) * 4);
    int*   counts  = (int*)alloc((size_t)N * 4);
    int*   bcur    = (int*)alloc((size_t)NB * 4);
    int2*  csr     = (int2*)alloc((size_t)E * 8);
    bf16_t* W1t    = (bf16_t*)alloc((size_t)NIN * NH * 2);  // [256][512]
    bf16_t* W3t    = (bf16_t*)alloc((size_t)NH * NH * 2);   // [256][256]
    bf16_t* W2t    = (bf16_t*)alloc((size_t)NH * NO * 2);   // [64][256]
    if (off > ws_size) return;  // visible absmax failure, not an OOB crash

    // --- build CSR (two-pass bucketed) + transposed bf16 weights ---
    zero_i32<<<(N + 255) / 256, 256, 0, stream>>>(counts, N);
    count_edges<<<(E + 255) / 256, 256, 0, stream>>>(erow, counts, E, N);
    scan_rows<<<1, 1024, 0, stream>>>(counts, row_ptr, N);
    init_bcur<<<(NB + 255) / 256, 256, 0, stream>>>(row_ptr, bcur, N, NB);
    bin_edges<<<(E + BIN_CHUNK - 1) / BIN_CHUNK, 256, 0, stream>>>(
        erow, ecol, ev, bcur, csr, E, N, NB);
    bucket_sort<<<NB, 256, 0, stream>>>(row_ptr, csr, N);
    transpose_w<<<(NIN * NH + 255) / 256, 256, 0, stream>>>(W1, W1t, NIN, NH);
    transpose_w<<<(NH * NH + 255) / 256, 256, 0, stream>>>(W3, W3t, NH, NH);
    transpose_w<<<(NH * NO + 255) / 256, 256, 0, stream>>>(W2, W2t, NH, NO);

    // --- x0 = relu(x @ W1 + b1): fp32 A, 128x128 tile ---
    dim3 g1((N + 127) / 128, NH / 128);
    mfma_gemm<2, 2, true, false, true, bf16_t><<<g1, 256, 0, stream>>>(
        x, W1t, b1, x0, N, NIN, NH);

    // --- 10 hops ---
    const bf16_t* hin = x0;
    for (int hop = 0; hop < 10; ++hop) {
        spmm_kernel<<<(N + 3) / 4, 256, 0, stream>>>(row_ptr, csr, hin, x0, A2, hB, N);
        mfma_gemm<2, 2, false, true, true, bf16_t><<<g1, 256, 0, stream>>>(
            hB, W3t, b3, hA, N, NH, NH);
        hin = hA;
    }

    // --- out = h @ W2 + b2: 256x64 tile (N=64) ---
    dim3 g2((N + 255) / 256, 1);
    mfma_gemm<4, 1, false, false, false, float><<<g2, 256, 0, stream>>>(
        hA, W2t, b2, out, N, NH, NO);
}

// Round 4
// 3366.554 us; speedup vs baseline: 1.0267x; 1.0267x over previous
//
#include <hip/hip_runtime.h>
#include <stdint.h>

// GTCN2 Round 9:
//  - Fused hop kernel: spmm (R8 gather structure, per-wave rows) writes its
//    128-row s-tile to LDS (XOR-swizzled, byte ^= (row&7)<<4), then the same
//    block runs the s@W3 GEMM from LDS with skip read from LDS. Eliminates
//    per hop: hB write (50MB) + GEMM A-stage read (102MB) + skip re-read
//    (51MB) + 1 launch. 80KB LDS -> 2 blocks/CU = 16 waves x 4KB in flight
//    (>= the 48KB that already saturated the gather fabric in R7).
//  - GEMM1 retiled to TM=64/TN=256 (fp32 A read once, not twice).
//  - Evidence from R8: gather path saturates at ~3.5TB/s regardless of
//    per-wave ILP -> spmm core left unchanged.

typedef unsigned short bf16_t;
typedef __attribute__((ext_vector_type(8))) short bf16x8;
typedef __attribute__((ext_vector_type(8))) unsigned short u16x8;
typedef __attribute__((ext_vector_type(4))) float f32x4;

__device__ __forceinline__ float bf2f(bf16_t u) {
    union { unsigned int i; float f; } v; v.i = ((unsigned int)u) << 16; return v.f;
}
__device__ __forceinline__ bf16_t f2bf(float f) {
    union { float f; unsigned int i; } v; v.f = f;
    unsigned int x = v.i;
    unsigned int r = (x + 0x7fffu + ((x >> 16) & 1u)) >> 16;  // RNE
    return (bf16_t)r;
}

__global__ void zero_i32(int* __restrict__ p, int n) {
    int i = blockIdx.x * blockDim.x + threadIdx.x;
    if (i < n) p[i] = 0;
}

// W: KxN fp32 -> Wt: NxK bf16 (so GEMM B-staging == A-staging pattern).
__global__ void transpose_w(const float* __restrict__ W, bf16_t* __restrict__ Wt,
                            int K, int N) {
    int i = blockIdx.x * blockDim.x + threadIdx.x;
    if (i < K * N) {
        int k = i / N, n = i % N;
        Wt[(size_t)n * K + k] = f2bf(W[i]);
    }
}

__global__ void count_edges(const int* __restrict__ er, int* __restrict__ cnt,
                            int E, int N) {
    int i = blockIdx.x * blockDim.x + threadIdx.x;
    if (i < E) {
        unsigned r = (unsigned)er[i];
        if (r < (unsigned)N) atomicAdd(&cnt[r], 1);
    }
}

__global__ __launch_bounds__(1024)
void scan_rows(int* cnt_cursor, int* __restrict__ row_ptr, int n) {
    __shared__ int sums[1024];
    int t = threadIdx.x;
    int chunk = (n + 1023) >> 10;
    int start = t * chunk;
    int end = min(start + chunk, n);
    int s = 0;
    for (int i = start; i < end; ++i) s += cnt_cursor[i];
    sums[t] = s;
    __syncthreads();
    for (int off = 1; off < 1024; off <<= 1) {
        int v = (t >= off) ? sums[t - off] : 0;
        __syncthreads();
        sums[t] += v;
        __syncthreads();
    }
    int run = (t == 0) ? 0 : sums[t - 1];
    for (int i = start; i < end; ++i) {
        int c = cnt_cursor[i];
        row_ptr[i] = run;
        run += c;
    }
    if (t == 1023) row_ptr[n] = sums[1023];
}

__global__ void init_bcur(const int* __restrict__ row_ptr, int* __restrict__ bcur,
                          int N, int NB) {
    int b = blockIdx.x * blockDim.x + threadIdx.x;
    if (b < NB) bcur[b] = row_ptr[min(b << 8, N)];
}

// Pass 1: bin edges into 256-row buckets. Packed entry: .x = r_local<<17 | c
// (c < 2^17), .y = float bits of val.
#define BIN_CHUNK 8192
#define NBMAX 392
__global__ __launch_bounds__(256)
void bin_edges(const int* __restrict__ er, const int* __restrict__ ec,
               const float* __restrict__ ev, int* __restrict__ bcur,
               int2* __restrict__ binned, int E, int N, int NB) {
    __shared__ int cnt[NBMAX];
    __shared__ int resv[NBMAX];
    int tid = threadIdx.x;
    int e0 = blockIdx.x * BIN_CHUNK;
    int n = min(BIN_CHUNK, E - e0);
    for (int b = tid; b < NB; b += 256) cnt[b] = 0;
    __syncthreads();
    for (int i = tid; i < n; i += 256) {
        unsigned r = (unsigned)er[e0 + i];
        if (r < (unsigned)N) atomicAdd(&cnt[r >> 8], 1);
    }
    __syncthreads();
    for (int b = tid; b < NB; b += 256) {
        int c = cnt[b];
        resv[b] = c ? atomicAdd(&bcur[b], c) : 0;
        cnt[b] = 0;  // reuse as local cursor
    }
    __syncthreads();
    for (int i = tid; i < n; i += 256) {
        unsigned r = (unsigned)er[e0 + i];
        if (r < (unsigned)N) {
            unsigned c = (unsigned)ec[e0 + i];
            float v = ev[e0 + i];
            if (c >= (unsigned)N) { c = 0; v = 0.f; }  // sanitize, keep slot
            int b = (int)(r >> 8);
            int p = resv[b] + atomicAdd(&cnt[b], 1);
            binned[p] = make_int2((int)(((r & 255u) << 17) | c), __float_as_int(v));
        }
    }
}

// Pass 2: sort one bucket into exact CSR row order, in place via LDS staging.
#define BCAP 9216
__global__ __launch_bounds__(256)
void bucket_sort(const int* __restrict__ row_ptr, int2* __restrict__ csr, int N) {
    __shared__ int2 ent[BCAP];
    __shared__ int cnt[256];
    __shared__ int base[256];
    __shared__ int lcur[256];
    int b = blockIdx.x;
    int tid = threadIdx.x;
    int r0 = b << 8;
    int e0 = row_ptr[r0];
    int e1 = row_ptr[min(r0 + 256, N)];
    int n = e1 - e0;
    cnt[tid] = 0;
    __syncthreads();
    for (int i = tid; i < n; i += 256) {
        int2 p = csr[e0 + i];
        if (i < BCAP) ent[i] = p;
        atomicAdd(&cnt[((unsigned)p.x >> 17) & 255u], 1);
    }
    __syncthreads();
    int v0 = cnt[tid];
    for (int off = 1; off < 256; off <<= 1) {
        int u = (tid >= off) ? cnt[tid - off] : 0;
        __syncthreads();
        cnt[tid] += u;
        __syncthreads();
    }
    base[tid] = cnt[tid] - v0;  // exclusive scan
    lcur[tid] = 0;
    __syncthreads();
    for (int i = tid; i < n; i += 256) {
        int2 p = (i < BCAP) ? ent[i] : csr[e0 + i];  // tail branch unreachable
        int rl = (int)(((unsigned)p.x >> 17) & 255u);
        int d = base[rl] + atomicAdd(&lcur[rl], 1);
        csr[e0 + d] = make_int2(p.x & 0x1FFFF, p.y);
    }
}

__device__ __forceinline__ void fma8(float* acc, float v, u16x8 hv) {
    #pragma unroll
    for (int k = 0; k < 8; ++k)
        acc[k] = fmaf(v, bf2f((bf16_t)hv[k]), acc[k]);
}

// Fused hop: block (512 thr, 8 waves) owns 128 rows.
//   Phase 1 (spmm): wave w computes rows w*16..w*16+15 sequentially with the
//     R8 gather loop (halves on different edges, 4KB in flight), writing bf16
//     results into the XOR-swizzled LDS s-tile.
//   Phase 2 (GEMM): out = relu(s + s@W3 + b3); A-frags from s-tile LDS
//     (swizzle -> conflict-free), B staged per k-step via global_load_lds,
//     skip term read from s-tile.
__global__ __launch_bounds__(512, 4)
void fused_hop(const int* __restrict__ row_ptr, const int2* __restrict__ csr,
               const bf16_t* __restrict__ hin, const bf16_t* __restrict__ x0,
               const float* __restrict__ A2, const bf16_t* __restrict__ W3t,
               const float* __restrict__ bias, bf16_t* __restrict__ hout, int M) {
    __shared__ bf16_t s_tile[128 * 256];   // 64 KB, row stride 512 B, swizzled
    __shared__ bf16_t Bs[256 * 32];        // 16 KB
    const int tid = threadIdx.x;
    const int w = tid >> 6, lane = tid & 63;
    const int bm = blockIdx.x * 128;
    const int half = lane >> 5, l32 = lane & 31, fo = l32 << 3;

    // ---- phase 1: spmm into s_tile ----
    for (int rr = 0; rr < 16; ++rr) {
        int lrow = w * 16 + rr;
        int row = bm + lrow;
        float acc[8];
        #pragma unroll
        for (int k = 0; k < 8; ++k) acc[k] = 0.f;
        if (row < M) {
            if (half == 0) {
                float a2 = A2[row];
                u16x8 xv = *(const u16x8*)&x0[(row << 8) + fo];
                #pragma unroll
                for (int k = 0; k < 8; ++k) acc[k] = a2 * bf2f((bf16_t)xv[k]);
            }
            int e = row_ptr[row], e1 = row_ptr[row + 1];
            int nb = (e1 - e) >> 3;
            int2 q0, q1, q2, q3;
            if (nb > 0) {
                int eb = e + half;
                q0 = csr[eb]; q1 = csr[eb + 2]; q2 = csr[eb + 4]; q3 = csr[eb + 6];
            }
            for (int b = 0; b < nb; ++b) {
                int2 p0 = q0, p1 = q1, p2 = q2, p3 = q3;
                if (b + 1 < nb) {
                    int eb = e + 8 + half;
                    q0 = csr[eb]; q1 = csr[eb + 2]; q2 = csr[eb + 4]; q3 = csr[eb + 6];
                }
                u16x8 h0 = *(const u16x8*)&hin[(p0.x << 8) + fo];
                u16x8 h1 = *(const u16x8*)&hin[(p1.x << 8) + fo];
                u16x8 h2 = *(const u16x8*)&hin[(p2.x << 8) + fo];
                u16x8 h3 = *(const u16x8*)&hin[(p3.x << 8) + fo];
                fma8(acc, __int_as_float(p0.y), h0);
                fma8(acc, __int_as_float(p1.y), h1);
                fma8(acc, __int_as_float(p2.y), h2);
                fma8(acc, __int_as_float(p3.y), h3);
                e += 8;
            }
            for (; e + 2 <= e1; e += 2) {
                int2 p = csr[e + half];
                u16x8 hv = *(const u16x8*)&hin[(p.x << 8) + fo];
                fma8(acc, __int_as_float(p.y), hv);
            }
            if (e < e1 && half == 0) {
                int2 p = csr[e];
                u16x8 hv = *(const u16x8*)&hin[(p.x << 8) + fo];
                fma8(acc, __int_as_float(p.y), hv);
            }
            #pragma unroll
            for (int k = 0; k < 8; ++k) acc[k] += __shfl_xor(acc[k], 32, 64);
        }
        if (half == 0) {
            u16x8 o;
            #pragma unroll
            for (int k = 0; k < 8; ++k) o[k] = f2bf(acc[k]);
            // swizzled write: byte = lrow*512 + ((l32*16) ^ ((lrow&7)<<4))
            *(u16x8*)((char*)s_tile + lrow * 512 + (((fo << 1)) ^ ((lrow & 7) << 4))) = o;
        }
    }
    __syncthreads();

    // ---- phase 2: GEMM relu(s + s@W3 + b3) ----
    const int q = lane >> 4, l16 = lane & 15;
    const int wm = (w & 1) * 64, wn = (w >> 1) * 64;  // 2x4 wave tiling
    f32x4 acc2[4][4] = {};
    for (int k0 = 0; k0 < 256; k0 += 32) {
        #pragma unroll
        for (int r = 0; r < 2; ++r) {
            int rowbase = r * 128 + w * 16;
            int row = rowbase + (lane >> 2);
            const bf16_t* gp = W3t + (size_t)row * 256 + k0 + (lane & 3) * 8;
            bf16_t* lp = Bs + rowbase * 32 + lane * 8;
            __builtin_amdgcn_global_load_lds(
                (const __attribute__((address_space(1))) unsigned int*)gp,
                (__attribute__((address_space(3))) unsigned int*)lp, 16, 0, 0);
        }
        __syncthreads();
        bf16x8 afr[4], bfr[4];
        #pragma unroll
        for (int ms = 0; ms < 4; ++ms) {
            int ar = wm + ms * 16 + l16;
            afr[ms] = *(const bf16x8*)((const char*)s_tile + ar * 512 +
                       ((((k0 + q * 8) << 1)) ^ ((ar & 7) << 4)));
        }
        #pragma unroll
        for (int ns = 0; ns < 4; ++ns)
            bfr[ns] = *(const bf16x8*)&Bs[(wn + ns * 16 + l16) * 32 + q * 8];
        #pragma unroll
        for (int ms = 0; ms < 4; ++ms)
            #pragma unroll
            for (int ns = 0; ns < 4; ++ns)
                acc2[ms][ns] = __builtin_amdgcn_mfma_f32_16x16x32_bf16(
                    afr[ms], bfr[ns], acc2[ms][ns], 0, 0, 0);
        __syncthreads();
    }

    // ---- epilogue: skip from LDS, bias, relu ----
    #pragma unroll
    for (int ms = 0; ms < 4; ++ms) {
        #pragma unroll
        for (int r = 0; r < 4; ++r) {
            int lrow = wm + ms * 16 + q * 4 + r;
            int grow = bm + lrow;
            if (grow < M) {
                #pragma unroll
                for (int ns = 0; ns < 4; ++ns) {
                    int col = wn + ns * 16 + l16;
                    float v = acc2[ms][ns][r] + bias[col];
                    v += bf2f(*(const bf16_t*)((const char*)s_tile + lrow * 512 +
                              (((col << 1)) ^ ((lrow & 7) << 4))));
                    v = fmaxf(v, 0.f);
                    hout[(size_t)grow * 256 + col] = f2bf(v);
                }
            }
        }
    }
}

// MFMA GEMM: C[M,Nfull] = epi(A[M,K] @ Bt[Nfull,K]^T). 4 waves, wave 64x64.
template <int WM, int WN, bool AF32, bool RELU, typename CT>
__global__ __launch_bounds__(256)
void mfma_gemm(const void* __restrict__ Av, const bf16_t* __restrict__ Bt,
               const float* __restrict__ bias, CT* __restrict__ C,
               int M, int K, int Nfull) {
    constexpr int TM = WM * 64;
    constexpr int TN = WN * 64;
    __shared__ bf16_t As[TM * 32];
    __shared__ bf16_t Bs[TN * 32];
    const int tid = threadIdx.x;
    const int w = tid >> 6, lane = tid & 63;
    const int q = lane >> 4, l16 = lane & 15;
    const int bm = blockIdx.x * TM;
    const int bn = blockIdx.y * TN;
    const int wm = (w % WM) * 64;
    const int wn = (w / WM) * 64;

    f32x4 acc[4][4] = {};

    for (int k0 = 0; k0 < K; k0 += 32) {
        // ---- stage A tile [TM][32] ----
        if constexpr (AF32) {
            // 256 threads cover TM*32 fp32: TM/8 elems per thread.
            constexpr int TPR = 256 / TM;      // threads per row
            constexpr int EPT = TM / 8;        // fp32 elems per thread
            const float* A = (const float*)Av;
            int row = tid / TPR;
            int gr = min(bm + row, M - 1);
            int off = (tid % TPR) * EPT;
            const float* src = A + (size_t)gr * K + k0 + off;
            bf16_t* dst = As + row * 32 + off;
            #pragma unroll
            for (int g = 0; g < EPT / 4; ++g) {
                float4 v = *(const float4*)(src + 4 * g);
                ushort4 u;
                u.x = f2bf(v.x); u.y = f2bf(v.y); u.z = f2bf(v.z); u.w = f2bf(v.w);
                *(ushort4*)(dst + 4 * g) = u;
            }
        } else {
            const bf16_t* A = (const bf16_t*)Av;
            #pragma unroll
            for (int r = 0; r < TM / 64; ++r) {
                int rowbase = r * 64 + w * 16;           // wave-uniform
                int row = rowbase + (lane >> 2);
                int gr = min(bm + row, M - 1);           // clamp tail rows
                const bf16_t* gp = A + (size_t)gr * K + k0 + (lane & 3) * 8;
                bf16_t* lp = As + rowbase * 32 + lane * 8;
                __builtin_amdgcn_global_load_lds(
                    (const __attribute__((address_space(1))) unsigned int*)gp,
                    (__attribute__((address_space(3))) unsigned int*)lp, 16, 0, 0);
            }
        }
        // ---- stage B tile [TN][32] from Bt (NxK row-major) ----
        #pragma unroll
        for (int r = 0; r < TN / 64; ++r) {
            int rowbase = r * 64 + w * 16;
            int row = rowbase + (lane >> 2);
            const bf16_t* gp = Bt + (size_t)(bn + row) * K + k0 + (lane & 3) * 8;
            bf16_t* lp = Bs + rowbase * 32 + lane * 8;
            __builtin_amdgcn_global_load_lds(
                (const __attribute__((address_space(1))) unsigned int*)gp,
                (__attribute__((address_space(3))) unsigned int*)lp, 16, 0, 0);
        }
        __syncthreads();

        bf16x8 afr[4], bfr[4];
        #pragma unroll
        for (int ms = 0; ms < 4; ++ms)
            afr[ms] = *(const bf16x8*)&As[(wm + ms * 16 + l16) * 32 + q * 8];
        #pragma unroll
        for (int ns = 0; ns < 4; ++ns)
            bfr[ns] = *(const bf16x8*)&Bs[(wn + ns * 16 + l16) * 32 + q * 8];
        #pragma unroll
        for (int ms = 0; ms < 4; ++ms)
            #pragma unroll
            for (int ns = 0; ns < 4; ++ns)
                acc[ms][ns] = __builtin_amdgcn_mfma_f32_16x16x32_bf16(
                    afr[ms], bfr[ns], acc[ms][ns], 0, 0, 0);
        __syncthreads();
    }

    // ---- epilogue ----
    #pragma unroll
    for (int ms = 0; ms < 4; ++ms) {
        #pragma unroll
        for (int r = 0; r < 4; ++r) {
            int row = bm + wm + ms * 16 + q * 4 + r;
            if (row < M) {
                #pragma unroll
                for (int ns = 0; ns < 4; ++ns) {
                    int col = bn + wn + ns * 16 + l16;
                    float v = acc[ms][ns][r] + bias[col];
                    if constexpr (RELU) v = fmaxf(v, 0.f);
                    if constexpr (sizeof(CT) == 2) C[(size_t)row * Nfull + col] = (CT)f2bf(v);
                    else                           C[(size_t)row * Nfull + col] = (CT)v;
                }
            }
        }
    }
}

extern "C" void kernel_launch(void* const* d_in, const int* in_sizes, int n_in,
                              void* d_out, int out_size, void* d_ws, size_t ws_size,
                              hipStream_t stream) {
    const float* x   = (const float*)d_in[0];
    const int* erow  = (const int*)d_in[1];
    const int* ecol  = (const int*)d_in[2];
    const float* ev  = (const float*)d_in[3];
    const float* A2  = (const float*)d_in[4];
    const float* W1  = (const float*)d_in[5];
    const float* b1  = (const float*)d_in[6];
    const float* W3  = (const float*)d_in[7];
    const float* b3  = (const float*)d_in[8];
    const float* W2  = (const float*)d_in[9];
    const float* b2  = (const float*)d_in[10];
    float* out = (float*)d_out;

    const int N   = in_sizes[4];        // 100000 nodes
    const int E   = in_sizes[1];        // 3200000 edges
    const int NIN = in_sizes[0] / N;    // 512
    const int NH  = in_sizes[6];        // 256
    const int NO  = in_sizes[10];       // 64
    if (NH != 256 || NIN != 512 || NO != 64) return;  // layout hard-coded
    const int NB = (N + 255) >> 8;      // 391 buckets
    if (NB > NBMAX) return;

    char* ws = (char*)d_ws;
    size_t off = 0;
    auto alloc = [&](size_t bytes) -> void* {
        void* p = ws + off;
        off += (bytes + 255) & ~(size_t)255;
        return p;
    };
    bf16_t* x0     = (bf16_t*)alloc((size_t)N * NH * 2);
    bf16_t* hA     = (bf16_t*)alloc((size_t)N * NH * 2);
    bf16_t* hB     = (bf16_t*)alloc((size_t)N * NH * 2);
    int*   row_ptr = (int*)alloc((size_t)(N + 1) * 4);
    int*   counts  = (int*)alloc((size_t)N * 4);
    int*   bcur    = (int*)alloc((size_t)NB * 4);
    int2*  csr     = (int2*)alloc((size_t)E * 8);
    bf16_t* W1t    = (bf16_t*)alloc((size_t)NIN * NH * 2);  // [256][512]
    bf16_t* W3t    = (bf16_t*)alloc((size_t)NH * NH * 2);   // [256][256]
    bf16_t* W2t    = (bf16_t*)alloc((size_t)NH * NO * 2);   // [64][256]
    if (off > ws_size) return;  // visible absmax failure, not an OOB crash

    // --- build CSR (two-pass bucketed) + transposed bf16 weights ---
    zero_i32<<<(N + 255) / 256, 256, 0, stream>>>(counts, N);
    count_edges<<<(E + 255) / 256, 256, 0, stream>>>(erow, counts, E, N);
    scan_rows<<<1, 1024, 0, stream>>>(counts, row_ptr, N);
    init_bcur<<<(NB + 255) / 256, 256, 0, stream>>>(row_ptr, bcur, N, NB);
    bin_edges<<<(E + BIN_CHUNK - 1) / BIN_CHUNK, 256, 0, stream>>>(
        erow, ecol, ev, bcur, csr, E, N, NB);
    bucket_sort<<<NB, 256, 0, stream>>>(row_ptr, csr, N);
    transpose_w<<<(NIN * NH + 255) / 256, 256, 0, stream>>>(W1, W1t, NIN, NH);
    transpose_w<<<(NH * NH + 255) / 256, 256, 0, stream>>>(W3, W3t, NH, NH);
    transpose_w<<<(NH * NO + 255) / 256, 256, 0, stream>>>(W2, W2t, NH, NO);

    // --- x0 = relu(x @ W1 + b1): fp32 A, 64x256 tile (A read once) ---
    dim3 g1((N + 63) / 64, 1);
    mfma_gemm<1, 4, true, true, bf16_t><<<g1, 256, 0, stream>>>(
        x, W1t, b1, x0, N, NIN, NH);

    // --- 10 fused hops ---
    const bf16_t* hin = x0;
    bf16_t* hout = hA;
    for (int hop = 0; hop < 10; ++hop) {
        fused_hop<<<(N + 127) / 128, 512, 0, stream>>>(
            row_ptr, csr, hin, x0, A2, W3t, b3, hout, N);
        hin = hout;
        hout = (hout == hA) ? hB : hA;
    }

    // --- out = h @ W2 + b2: 256x64 tile (N=64) ---
    dim3 g2((N + 255) / 256, 1);
    mfma_gemm<4, 1, false, false, float><<<g2, 256, 0, stream>>>(
        (const void*)hin, W2t, b2, out, N, NH, NO);
}

// Round 5
// 3092.213 us; speedup vs baseline: 1.1178x; 1.0887x over previous
//
#include <hip/hip_runtime.h>
#include <stdint.h>

// GTCN2 Round 10:
//  - fused_hop retiled to 64-row blocks (s_tile 32KB + Bs 16KB = 48KB LDS)
//    -> 3 blocks/CU = 24 waves (was 16) and 2x finer grid (1563 blocks) to
//    fix the occupancy collapse (35.5%) + tail that slowed the gather phase
//    to 3.2TB/s in R9. GEMM phase: 8 waves x 32x64 sub-tiles.
//  - CSR build: count_edges (3.2M atomics / 100K ctrs) and single-block
//    scan_rows removed; bucket-level histogram (391 ctrs, LDS-aggregated) +
//    391-wide scan; bucket_sort emits row_ptr from its in-LDS row scan.

typedef unsigned short bf16_t;
typedef __attribute__((ext_vector_type(8))) short bf16x8;
typedef __attribute__((ext_vector_type(8))) unsigned short u16x8;
typedef __attribute__((ext_vector_type(4))) float f32x4;

__device__ __forceinline__ float bf2f(bf16_t u) {
    union { unsigned int i; float f; } v; v.i = ((unsigned int)u) << 16; return v.f;
}
__device__ __forceinline__ bf16_t f2bf(float f) {
    union { float f; unsigned int i; } v; v.f = f;
    unsigned int x = v.i;
    unsigned int r = (x + 0x7fffu + ((x >> 16) & 1u)) >> 16;  // RNE
    return (bf16_t)r;
}

__global__ void zero_i32(int* __restrict__ p, int n) {
    int i = blockIdx.x * blockDim.x + threadIdx.x;
    if (i < n) p[i] = 0;
}

// W: KxN fp32 -> Wt: NxK bf16 (so GEMM B-staging == A-staging pattern).
__global__ void transpose_w(const float* __restrict__ W, bf16_t* __restrict__ Wt,
                            int K, int N) {
    int i = blockIdx.x * blockDim.x + threadIdx.x;
    if (i < K * N) {
        int k = i / N, n = i % N;
        Wt[(size_t)n * K + k] = f2bf(W[i]);
    }
}

#define BIN_CHUNK 8192
#define NBMAX 392

// Bucket-level histogram: LDS-aggregated, <=NB global atomics per block.
__global__ __launch_bounds__(256)
void bin_count(const int* __restrict__ er, int* __restrict__ bcnt, int E, int N,
               int NB) {
    __shared__ int cnt[NBMAX];
    int tid = threadIdx.x;
    for (int b = tid; b < NB; b += 256) cnt[b] = 0;
    __syncthreads();
    int e0 = blockIdx.x * BIN_CHUNK;
    int n = min(BIN_CHUNK, E - e0);
    for (int i = tid; i < n; i += 256) {
        unsigned r = (unsigned)er[e0 + i];
        if (r < (unsigned)N) atomicAdd(&cnt[r >> 8], 1);
    }
    __syncthreads();
    for (int b = tid; b < NB; b += 256) {
        int c = cnt[b];
        if (c) atomicAdd(&bcnt[b], c);
    }
}

// Exclusive scan over NB (<512) bucket counts -> bucket_base[NB+1], bcur copy.
__global__ __launch_bounds__(512)
void scan_buckets(const int* __restrict__ bcnt, int* __restrict__ bucket_base,
                  int* __restrict__ bcur, int NB) {
    __shared__ int s[512];
    int t = threadIdx.x;
    int v = (t < NB) ? bcnt[t] : 0;
    s[t] = v;
    __syncthreads();
    for (int off = 1; off < 512; off <<= 1) {
        int u = (t >= off) ? s[t - off] : 0;
        __syncthreads();
        s[t] += u;
        __syncthreads();
    }
    if (t < NB) {
        int excl = s[t] - v;
        bucket_base[t] = excl;
        bcur[t] = excl;
        if (t == NB - 1) bucket_base[NB] = s[t];
    }
}

// Pass 1: bin edges into 256-row buckets. Packed entry: .x = r_local<<17 | c
// (c < 2^17), .y = float bits of val.
__global__ __launch_bounds__(256)
void bin_edges(const int* __restrict__ er, const int* __restrict__ ec,
               const float* __restrict__ ev, int* __restrict__ bcur,
               int2* __restrict__ binned, int E, int N, int NB) {
    __shared__ int cnt[NBMAX];
    __shared__ int resv[NBMAX];
    int tid = threadIdx.x;
    int e0 = blockIdx.x * BIN_CHUNK;
    int n = min(BIN_CHUNK, E - e0);
    for (int b = tid; b < NB; b += 256) cnt[b] = 0;
    __syncthreads();
    for (int i = tid; i < n; i += 256) {
        unsigned r = (unsigned)er[e0 + i];
        if (r < (unsigned)N) atomicAdd(&cnt[r >> 8], 1);
    }
    __syncthreads();
    for (int b = tid; b < NB; b += 256) {
        int c = cnt[b];
        resv[b] = c ? atomicAdd(&bcur[b], c) : 0;
        cnt[b] = 0;  // reuse as local cursor
    }
    __syncthreads();
    for (int i = tid; i < n; i += 256) {
        unsigned r = (unsigned)er[e0 + i];
        if (r < (unsigned)N) {
            unsigned c = (unsigned)ec[e0 + i];
            float v = ev[e0 + i];
            if (c >= (unsigned)N) { c = 0; v = 0.f; }  // sanitize, keep slot
            int b = (int)(r >> 8);
            int p = resv[b] + atomicAdd(&cnt[b], 1);
            binned[p] = make_int2((int)(((r & 255u) << 17) | c), __float_as_int(v));
        }
    }
}

// Pass 2: sort one bucket into exact CSR row order (in place via LDS staging)
// and emit row_ptr for its 256 rows from the in-LDS scan.
#define BCAP 9216
__global__ __launch_bounds__(256)
void bucket_sort(const int* __restrict__ bucket_base, int2* __restrict__ csr,
                 int* __restrict__ row_ptr, int N, int NB) {
    __shared__ int2 ent[BCAP];
    __shared__ int cnt[256];
    __shared__ int base[256];
    __shared__ int lcur[256];
    int b = blockIdx.x;
    int tid = threadIdx.x;
    int r0 = b << 8;
    int e0 = bucket_base[b];
    int e1 = bucket_base[b + 1];
    int n = e1 - e0;
    cnt[tid] = 0;
    __syncthreads();
    for (int i = tid; i < n; i += 256) {
        int2 p = csr[e0 + i];
        if (i < BCAP) ent[i] = p;
        atomicAdd(&cnt[((unsigned)p.x >> 17) & 255u], 1);
    }
    __syncthreads();
    int v0 = cnt[tid];
    for (int off = 1; off < 256; off <<= 1) {
        int u = (tid >= off) ? cnt[tid - off] : 0;
        __syncthreads();
        cnt[tid] += u;
        __syncthreads();
    }
    base[tid] = cnt[tid] - v0;  // exclusive scan
    lcur[tid] = 0;
    if (r0 + tid < N) row_ptr[r0 + tid] = e0 + cnt[tid] - v0;
    if (b == NB - 1 && tid == 255) row_ptr[N] = e1;
    __syncthreads();
    for (int i = tid; i < n; i += 256) {
        int2 p = (i < BCAP) ? ent[i] : csr[e0 + i];  // tail branch unreachable
        int rl = (int)(((unsigned)p.x >> 17) & 255u);
        int d = base[rl] + atomicAdd(&lcur[rl], 1);
        csr[e0 + d] = make_int2(p.x & 0x1FFFF, p.y);
    }
}

__device__ __forceinline__ void fma8(float* acc, float v, u16x8 hv) {
    #pragma unroll
    for (int k = 0; k < 8; ++k)
        acc[k] = fmaf(v, bf2f((bf16_t)hv[k]), acc[k]);
}

// Fused hop: block (512 thr, 8 waves) owns 64 rows. 48KB LDS -> 3 blocks/CU
// = 24 waves (gather fabric saturates at ~24 waves/CU per R7/R8).
//   Phase 1 (spmm): wave w computes rows w*8..w*8+7 with the R8 gather loop
//     (halves on different edges, 4KB in flight), results -> XOR-swizzled
//     LDS s_tile (byte ^= (row&7)<<4).
//   Phase 2 (GEMM): out = relu(s + s@W3 + b3); A-frags from s_tile,
//     B staged per k-step via global_load_lds, skip read from s_tile.
__global__ __launch_bounds__(512, 6)
void fused_hop(const int* __restrict__ row_ptr, const int2* __restrict__ csr,
               const bf16_t* __restrict__ hin, const bf16_t* __restrict__ x0,
               const float* __restrict__ A2, const bf16_t* __restrict__ W3t,
               const float* __restrict__ bias, bf16_t* __restrict__ hout, int M) {
    __shared__ bf16_t s_tile[64 * 256];    // 32 KB, row stride 512 B, swizzled
    __shared__ bf16_t Bs[256 * 32];        // 16 KB
    const int tid = threadIdx.x;
    const int w = tid >> 6, lane = tid & 63;
    const int bm = blockIdx.x * 64;
    const int half = lane >> 5, l32 = lane & 31, fo = l32 << 3;

    // ---- phase 1: spmm into s_tile ----
    for (int rr = 0; rr < 8; ++rr) {
        int lrow = w * 8 + rr;
        int row = bm + lrow;
        float acc[8];
        #pragma unroll
        for (int k = 0; k < 8; ++k) acc[k] = 0.f;
        if (row < M) {
            if (half == 0) {
                float a2 = A2[row];
                u16x8 xv = *(const u16x8*)&x0[(row << 8) + fo];
                #pragma unroll
                for (int k = 0; k < 8; ++k) acc[k] = a2 * bf2f((bf16_t)xv[k]);
            }
            int e = row_ptr[row], e1 = row_ptr[row + 1];
            int nb = (e1 - e) >> 3;
            int2 q0, q1, q2, q3;
            if (nb > 0) {
                int eb = e + half;
                q0 = csr[eb]; q1 = csr[eb + 2]; q2 = csr[eb + 4]; q3 = csr[eb + 6];
            }
            for (int b = 0; b < nb; ++b) {
                int2 p0 = q0, p1 = q1, p2 = q2, p3 = q3;
                if (b + 1 < nb) {
                    int eb = e + 8 + half;
                    q0 = csr[eb]; q1 = csr[eb + 2]; q2 = csr[eb + 4]; q3 = csr[eb + 6];
                }
                u16x8 h0 = *(const u16x8*)&hin[(p0.x << 8) + fo];
                u16x8 h1 = *(const u16x8*)&hin[(p1.x << 8) + fo];
                u16x8 h2 = *(const u16x8*)&hin[(p2.x << 8) + fo];
                u16x8 h3 = *(const u16x8*)&hin[(p3.x << 8) + fo];
                fma8(acc, __int_as_float(p0.y), h0);
                fma8(acc, __int_as_float(p1.y), h1);
                fma8(acc, __int_as_float(p2.y), h2);
                fma8(acc, __int_as_float(p3.y), h3);
                e += 8;
            }
            for (; e + 2 <= e1; e += 2) {
                int2 p = csr[e + half];
                u16x8 hv = *(const u16x8*)&hin[(p.x << 8) + fo];
                fma8(acc, __int_as_float(p.y), hv);
            }
            if (e < e1 && half == 0) {
                int2 p = csr[e];
                u16x8 hv = *(const u16x8*)&hin[(p.x << 8) + fo];
                fma8(acc, __int_as_float(p.y), hv);
            }
            #pragma unroll
            for (int k = 0; k < 8; ++k) acc[k] += __shfl_xor(acc[k], 32, 64);
        }
        if (half == 0) {
            u16x8 o;
            #pragma unroll
            for (int k = 0; k < 8; ++k) o[k] = f2bf(acc[k]);
            *(u16x8*)((char*)s_tile + lrow * 512 + ((fo << 1) ^ ((lrow & 7) << 4))) = o;
        }
    }
    __syncthreads();

    // ---- phase 2: GEMM relu(s + s@W3 + b3), 8 waves x 32x64 sub-tiles ----
    const int q = lane >> 4, l16 = lane & 15;
    const int wm = (w & 1) * 32, wn = (w >> 1) * 64;
    f32x4 acc2[2][4] = {};
    for (int k0 = 0; k0 < 256; k0 += 32) {
        #pragma unroll
        for (int r = 0; r < 2; ++r) {
            int rowbase = r * 128 + w * 16;
            int row = rowbase + (lane >> 2);
            const bf16_t* gp = W3t + (size_t)row * 256 + k0 + (lane & 3) * 8;
            bf16_t* lp = Bs + rowbase * 32 + lane * 8;
            __builtin_amdgcn_global_load_lds(
                (const __attribute__((address_space(1))) unsigned int*)gp,
                (__attribute__((address_space(3))) unsigned int*)lp, 16, 0, 0);
        }
        __syncthreads();
        bf16x8 afr[2], bfr[4];
        #pragma unroll
        for (int ms = 0; ms < 2; ++ms) {
            int ar = wm + ms * 16 + l16;
            afr[ms] = *(const bf16x8*)((const char*)s_tile + ar * 512 +
                       (((k0 + q * 8) << 1) ^ ((ar & 7) << 4)));
        }
        #pragma unroll
        for (int ns = 0; ns < 4; ++ns)
            bfr[ns] = *(const bf16x8*)&Bs[(wn + ns * 16 + l16) * 32 + q * 8];
        #pragma unroll
        for (int ms = 0; ms < 2; ++ms)
            #pragma unroll
            for (int ns = 0; ns < 4; ++ns)
                acc2[ms][ns] = __builtin_amdgcn_mfma_f32_16x16x32_bf16(
                    afr[ms], bfr[ns], acc2[ms][ns], 0, 0, 0);
        __syncthreads();
    }

    // ---- epilogue: skip from LDS, bias, relu ----
    #pragma unroll
    for (int ms = 0; ms < 2; ++ms) {
        #pragma unroll
        for (int r = 0; r < 4; ++r) {
            int lrow = wm + ms * 16 + q * 4 + r;
            int grow = bm + lrow;
            if (grow < M) {
                #pragma unroll
                for (int ns = 0; ns < 4; ++ns) {
                    int col = wn + ns * 16 + l16;
                    float v = acc2[ms][ns][r] + bias[col];
                    v += bf2f(*(const bf16_t*)((const char*)s_tile + lrow * 512 +
                              ((col << 1) ^ ((lrow & 7) << 4))));
                    v = fmaxf(v, 0.f);
                    hout[(size_t)grow * 256 + col] = f2bf(v);
                }
            }
        }
    }
}

// MFMA GEMM: C[M,Nfull] = epi(A[M,K] @ Bt[Nfull,K]^T). 4 waves, wave 64x64.
template <int WM, int WN, bool AF32, bool RELU, typename CT>
__global__ __launch_bounds__(256)
void mfma_gemm(const void* __restrict__ Av, const bf16_t* __restrict__ Bt,
               const float* __restrict__ bias, CT* __restrict__ C,
               int M, int K, int Nfull) {
    constexpr int TM = WM * 64;
    constexpr int TN = WN * 64;
    __shared__ bf16_t As[TM * 32];
    __shared__ bf16_t Bs[TN * 32];
    const int tid = threadIdx.x;
    const int w = tid >> 6, lane = tid & 63;
    const int q = lane >> 4, l16 = lane & 15;
    const int bm = blockIdx.x * TM;
    const int bn = blockIdx.y * TN;
    const int wm = (w % WM) * 64;
    const int wn = (w / WM) * 64;

    f32x4 acc[4][4] = {};

    for (int k0 = 0; k0 < K; k0 += 32) {
        // ---- stage A tile [TM][32] ----
        if constexpr (AF32) {
            constexpr int TPR = 256 / TM;      // threads per row
            constexpr int EPT = TM / 8;        // fp32 elems per thread
            const float* A = (const float*)Av;
            int row = tid / TPR;
            int gr = min(bm + row, M - 1);
            int off = (tid % TPR) * EPT;
            const float* src = A + (size_t)gr * K + k0 + off;
            bf16_t* dst = As + row * 32 + off;
            #pragma unroll
            for (int g = 0; g < EPT / 4; ++g) {
                float4 v = *(const float4*)(src + 4 * g);
                ushort4 u;
                u.x = f2bf(v.x); u.y = f2bf(v.y); u.z = f2bf(v.z); u.w = f2bf(v.w);
                *(ushort4*)(dst + 4 * g) = u;
            }
        } else {
            const bf16_t* A = (const bf16_t*)Av;
            #pragma unroll
            for (int r = 0; r < TM / 64; ++r) {
                int rowbase = r * 64 + w * 16;           // wave-uniform
                int row = rowbase + (lane >> 2);
                int gr = min(bm + row, M - 1);           // clamp tail rows
                const bf16_t* gp = A + (size_t)gr * K + k0 + (lane & 3) * 8;
                bf16_t* lp = As + rowbase * 32 + lane * 8;
                __builtin_amdgcn_global_load_lds(
                    (const __attribute__((address_space(1))) unsigned int*)gp,
                    (__attribute__((address_space(3))) unsigned int*)lp, 16, 0, 0);
            }
        }
        // ---- stage B tile [TN][32] from Bt (NxK row-major) ----
        #pragma unroll
        for (int r = 0; r < TN / 64; ++r) {
            int rowbase = r * 64 + w * 16;
            int row = rowbase + (lane >> 2);
            const bf16_t* gp = Bt + (size_t)(bn + row) * K + k0 + (lane & 3) * 8;
            bf16_t* lp = Bs + rowbase * 32 + lane * 8;
            __builtin_amdgcn_global_load_lds(
                (const __attribute__((address_space(1))) unsigned int*)gp,
                (__attribute__((address_space(3))) unsigned int*)lp, 16, 0, 0);
        }
        __syncthreads();

        bf16x8 afr[4], bfr[4];
        #pragma unroll
        for (int ms = 0; ms < 4; ++ms)
            afr[ms] = *(const bf16x8*)&As[(wm + ms * 16 + l16) * 32 + q * 8];
        #pragma unroll
        for (int ns = 0; ns < 4; ++ns)
            bfr[ns] = *(const bf16x8*)&Bs[(wn + ns * 16 + l16) * 32 + q * 8];
        #pragma unroll
        for (int ms = 0; ms < 4; ++ms)
            #pragma unroll
            for (int ns = 0; ns < 4; ++ns)
                acc[ms][ns] = __builtin_amdgcn_mfma_f32_16x16x32_bf16(
                    afr[ms], bfr[ns], acc[ms][ns], 0, 0, 0);
        __syncthreads();
    }

    // ---- epilogue ----
    #pragma unroll
    for (int ms = 0; ms < 4; ++ms) {
        #pragma unroll
        for (int r = 0; r < 4; ++r) {
            int row = bm + wm + ms * 16 + q * 4 + r;
            if (row < M) {
                #pragma unroll
                for (int ns = 0; ns < 4; ++ns) {
                    int col = bn + wn + ns * 16 + l16;
                    float v = acc[ms][ns][r] + bias[col];
                    if constexpr (RELU) v = fmaxf(v, 0.f);
                    if constexpr (sizeof(CT) == 2) C[(size_t)row * Nfull + col] = (CT)f2bf(v);
                    else                           C[(size_t)row * Nfull + col] = (CT)v;
                }
            }
        }
    }
}

extern "C" void kernel_launch(void* const* d_in, const int* in_sizes, int n_in,
                              void* d_out, int out_size, void* d_ws, size_t ws_size,
                              hipStream_t stream) {
    const float* x   = (const float*)d_in[0];
    const int* erow  = (const int*)d_in[1];
    const int* ecol  = (const int*)d_in[2];
    const float* ev  = (const float*)d_in[3];
    const float* A2  = (const float*)d_in[4];
    const float* W1  = (const float*)d_in[5];
    const float* b1  = (const float*)d_in[6];
    const float* W3  = (const float*)d_in[7];
    const float* b3  = (const float*)d_in[8];
    const float* W2  = (const float*)d_in[9];
    const float* b2  = (const float*)d_in[10];
    float* out = (float*)d_out;

    const int N   = in_sizes[4];        // 100000 nodes
    const int E   = in_sizes[1];        // 3200000 edges
    const int NIN = in_sizes[0] / N;    // 512
    const int NH  = in_sizes[6];        // 256
    const int NO  = in_sizes[10];       // 64
    if (NH != 256 || NIN != 512 || NO != 64) return;  // layout hard-coded
    const int NB = (N + 255) >> 8;      // 391 buckets
    if (NB > NBMAX) return;

    char* ws = (char*)d_ws;
    size_t off = 0;
    auto alloc = [&](size_t bytes) -> void* {
        void* p = ws + off;
        off += (bytes + 255) & ~(size_t)255;
        return p;
    };
    bf16_t* x0     = (bf16_t*)alloc((size_t)N * NH * 2);
    bf16_t* hA     = (bf16_t*)alloc((size_t)N * NH * 2);
    bf16_t* hB     = (bf16_t*)alloc((size_t)N * NH * 2);
    int*   row_ptr = (int*)alloc((size_t)(N + 1) * 4);
    int*   bcnt    = (int*)alloc((size_t)NB * 4);
    int*   bbase   = (int*)alloc((size_t)(NB + 1) * 4);
    int*   bcur    = (int*)alloc((size_t)NB * 4);
    int2*  csr     = (int2*)alloc((size_t)E * 8);
    bf16_t* W1t    = (bf16_t*)alloc((size_t)NIN * NH * 2);  // [256][512]
    bf16_t* W3t    = (bf16_t*)alloc((size_t)NH * NH * 2);   // [256][256]
    bf16_t* W2t    = (bf16_t*)alloc((size_t)NH * NO * 2);   // [64][256]
    if (off > ws_size) return;  // visible absmax failure, not an OOB crash

    // --- build CSR (two-pass bucketed, bucket-level counting) ---
    zero_i32<<<1, 512, 0, stream>>>(bcnt, NB);
    bin_count<<<(E + BIN_CHUNK - 1) / BIN_CHUNK, 256, 0, stream>>>(
        erow, bcnt, E, N, NB);
    scan_buckets<<<1, 512, 0, stream>>>(bcnt, bbase, bcur, NB);
    bin_edges<<<(E + BIN_CHUNK - 1) / BIN_CHUNK, 256, 0, stream>>>(
        erow, ecol, ev, bcur, csr, E, N, NB);
    bucket_sort<<<NB, 256, 0, stream>>>(bbase, csr, row_ptr, N, NB);
    transpose_w<<<(NIN * NH + 255) / 256, 256, 0, stream>>>(W1, W1t, NIN, NH);
    transpose_w<<<(NH * NH + 255) / 256, 256, 0, stream>>>(W3, W3t, NH, NH);
    transpose_w<<<(NH * NO + 255) / 256, 256, 0, stream>>>(W2, W2t, NH, NO);

    // --- x0 = relu(x @ W1 + b1): fp32 A, 64x256 tile (A read once) ---
    dim3 g1((N + 63) / 64, 1);
    mfma_gemm<1, 4, true, true, bf16_t><<<g1, 256, 0, stream>>>(
        x, W1t, b1, x0, N, NIN, NH);

    // --- 10 fused hops ---
    const bf16_t* hin = x0;
    bf16_t* hout = hA;
    for (int hop = 0; hop < 10; ++hop) {
        fused_hop<<<(N + 63) / 64, 512, 0, stream>>>(
            row_ptr, csr, hin, x0, A2, W3t, b3, hout, N);
        hin = hout;
        hout = (hout == hA) ? hB : hA;
    }

    // --- out = h @ W2 + b2: 256x64 tile (N=64) ---
    dim3 g2((N + 255) / 256, 1);
    mfma_gemm<4, 1, false, false, float><<<g2, 256, 0, stream>>>(
        (const void*)hin, W2t, b2, out, N, NH, NO);
}